// Round 1
// baseline (24.032 us; speedup 1.0000x reference)
//
#include <hip/hip_runtime.h>
#include <math.h>

#define CLASS_P 360
#define ROW_STRIDE 4320      // C * P = 12 * 360
#define NF4 90               // float4 chunks per window (360/4)

__device__ __forceinline__ float wave_sum(float v) {
    #pragma unroll
    for (int o = 32; o > 0; o >>= 1) v += __shfl_xor(v, o);
    return v;
}
__device__ __forceinline__ float wave_max(float v) {
    #pragma unroll
    for (int o = 32; o > 0; o >>= 1) v = fmaxf(v, __shfl_xor(v, o));
    return v;
}

// One 64-lane wave per row. 4 rows per 256-thread block.
__global__ __launch_bounds__(256) void vp_loss_rows(
        const float* __restrict__ preds,
        const float* __restrict__ labels,
        const int*   __restrict__ cls,
        float* __restrict__ partial,
        int B) {
    const int row  = blockIdx.x * 4 + (threadIdx.x >> 6);
    const int lane = threadIdx.x & 63;
    if (row >= B) return;

    const size_t base = (size_t)row * ROW_STRIDE + (size_t)cls[row] * CLASS_P;
    const float4* __restrict__ p4 = (const float4*)(preds + base);
    const float4* __restrict__ l4 = (const float4*)(labels + base);

    // Lane i holds float4 i (i<64) and float4 i+64 (i<26): 90 float4 total.
    float4 a0 = p4[lane];
    float4 b0 = l4[lane];
    const bool has2 = lane < (NF4 - 64);   // lane < 26
    float4 a1 = make_float4(0.f, 0.f, 0.f, 0.f);
    float4 b1 = a1;
    if (has2) { a1 = p4[lane + 64]; b1 = l4[lane + 64]; }

    // Phase 1: L1 norm and max of the window (fused wave reductions).
    float sabs = fabsf(a0.x) + fabsf(a0.y) + fabsf(a0.z) + fabsf(a0.w);
    float pmax = fmaxf(fmaxf(a0.x, a0.y), fmaxf(a0.z, a0.w));
    if (has2) {
        sabs += fabsf(a1.x) + fabsf(a1.y) + fabsf(a1.z) + fabsf(a1.w);
        pmax  = fmaxf(pmax, fmaxf(fmaxf(a1.x, a1.y), fmaxf(a1.z, a1.w)));
    }
    sabs = wave_sum(sabs);
    pmax = wave_max(pmax);

    const float inv = 1.0f / sabs;     // scaled_j = pw_j * inv
    const float m   = pmax * inv;      // max(scaled) (inv > 0, monotone)

    // Phase 2: sum exp(scaled - m)
    float se = __expf(a0.x * inv - m) + __expf(a0.y * inv - m)
             + __expf(a0.z * inv - m) + __expf(a0.w * inv - m);
    if (has2)
        se += __expf(a1.x * inv - m) + __expf(a1.y * inv - m)
            + __expf(a1.z * inv - m) + __expf(a1.w * inv - m);
    se = wave_sum(se);
    const float lse = __logf(se) + m;  // logsumexp(scaled)

    // Phase 3: -sum lw * (scaled - lse)  ==  sum lw * (lse - scaled)
    float acc = b0.x * (lse - a0.x * inv) + b0.y * (lse - a0.y * inv)
              + b0.z * (lse - a0.z * inv) + b0.w * (lse - a0.w * inv);
    if (has2)
        acc += b1.x * (lse - a1.x * inv) + b1.y * (lse - a1.y * inv)
             + b1.z * (lse - a1.z * inv) + b1.w * (lse - a1.w * inv);
    acc = wave_sum(acc);

    if (lane == 0) partial[row] = acc;
}

// Single-block deterministic reduction of B partials -> out[0].
__global__ __launch_bounds__(512) void vp_loss_reduce(
        const float* __restrict__ partial, float* __restrict__ out, int n) {
    __shared__ float sm[8];
    float acc = 0.f;
    for (int i = threadIdx.x; i < n; i += 512) acc += partial[i];
    acc = wave_sum(acc);
    const int wid = threadIdx.x >> 6, lane = threadIdx.x & 63;
    if (lane == 0) sm[wid] = acc;
    __syncthreads();
    if (wid == 0) {
        float v = (lane < 8) ? sm[lane] : 0.f;
        v = wave_sum(v);
        if (lane == 0) out[0] = v;
    }
}

extern "C" void kernel_launch(void* const* d_in, const int* in_sizes, int n_in,
                              void* d_out, int out_size, void* d_ws, size_t ws_size,
                              hipStream_t stream) {
    const float* preds  = (const float*)d_in[0];
    const float* labels = (const float*)d_in[1];
    const int*   cls    = (const int*)d_in[2];
    float* out = (float*)d_out;
    float* ws  = (float*)d_ws;

    const int B = in_sizes[2];               // 16384 rows
    const int blocks = (B + 3) / 4;          // 4 rows (waves) per block

    vp_loss_rows<<<blocks, 256, 0, stream>>>(preds, labels, cls, ws, B);
    vp_loss_reduce<<<1, 512, 0, stream>>>(ws, out, B);
}